// Round 1
// baseline (7847.431 us; speedup 1.0000x reference)
//
#include <hip/hip_runtime.h>
#include <cmath>

#define NB   8
#define NPG  128
#define NN   1024
#define KNB  64
#define HD   600
#define GG   50
#define LL   6
#define EE   (NN*KNB)   // 65536 edges

// ---------------- graph build ----------------
__global__ __launch_bounds__(64) void build_graph_k(const float* __restrict__ pos,
        int* __restrict__ nbr, float* __restrict__ dist, float* __restrict__ cval) {
#pragma clang fp contract(off)
  int i = blockIdx.x * 64 + threadIdx.x;
  if (i >= NN) return;
  int b = i >> 7;
  int li = i & 127;
  int base = b * NPG;
  float px = pos[3*i], py = pos[3*i+1], pz = pos[3*i+2];
  float bd[KNB]; int bi[KNB]; int cnt = 0;
  for (int j = 0; j < NPG; ++j) {
    if (j == li) continue;
    int gj = base + j;
    float dx = px - pos[3*gj], dy = py - pos[3*gj+1], dz = pz - pos[3*gj+2];
    float d2 = dx*dx + dy*dy + dz*dz;
    if (d2 > 100.0f) continue;
    if (cnt < KNB) {
      int p = cnt++;
      while (p > 0 && bd[p-1] > d2) { bd[p]=bd[p-1]; bi[p]=bi[p-1]; --p; }
      bd[p] = d2; bi[p] = j;
    } else if (d2 < bd[KNB-1]) {
      int p = KNB-1;
      while (p > 0 && bd[p-1] > d2) { bd[p]=bd[p-1]; bi[p]=bi[p-1]; --p; }
      bd[p] = d2; bi[p] = j;
    }
  }
  for (int k = 0; k < KNB; ++k) {
    int e = i*KNB + k;
    if (k < cnt) {
      nbr[e] = base + bi[k];
      float d = sqrtf(bd[k]);
      dist[e] = d;
      cval[e] = 0.5f * (cosf(d * 3.14159265358979f / 10.0f) + 1.0f);
    } else {
      nbr[e] = i; dist[e] = 0.0f; cval[e] = 0.0f;
    }
  }
}

// ---------------- gaussian smearing (layer-independent) ----------------
__global__ __launch_bounds__(256) void ea_k(const float* __restrict__ dist,
                                            float* __restrict__ ea) {
  int idx = blockIdx.x*256 + threadIdx.x;
  if (idx >= EE*GG) return;
  int e = idx / GG;
  int g = idx - e*GG;
  const float step = 10.0f/49.0f;
  const float coeff = -0.5f/(step*step);
  float dd = dist[e] - step*(float)g;
  ea[idx] = expf(coeff*dd*dd);
}

// ---------------- embedding ----------------
__global__ __launch_bounds__(256) void embed_k(const int* __restrict__ z,
        const float* __restrict__ emb, float* __restrict__ h) {
  int i = blockIdx.x;
  int zi = z[i];
  for (int j = threadIdx.x; j < HD; j += 256)
    h[(size_t)i*HD + j] = emb[(size_t)zi*HD + j];
}

// ---------------- shifted softplus ----------------
__device__ __forceinline__ float sspf(float x) {
  float sp = (x > 20.0f) ? x : log1pf(expf(x));
  return sp - 0.69314718055994531f;
}

// ---------------- tiled fp32 GEMM: C = op(A@B [+ bias]) ----------------
// MODE 0: C = A@B          MODE 1: C = ssp(A@B + bias)      MODE 2: C += A@B + bias
#define BM 64
#define BN 64
#define BK 16

template<int MODE>
__global__ __launch_bounds__(256) void gemm_k(const float* __restrict__ A,
    const float* __restrict__ Bw, const float* __restrict__ bias,
    float* __restrict__ Cout, int M, int N, int Kd) {
  __shared__ float As[BK][BM];
  __shared__ float Bs[BK][BN];
  int tid = threadIdx.x;
  int m0 = blockIdx.x * BM, n0 = blockIdx.y * BN;
  int tr = tid >> 4, tc = tid & 15;
  float acc[4][4] = {};
  int la_m = tid >> 2, la_q = (tid & 3) * 4;
  int lb_k = tid >> 4, lb_j = (tid & 15) * 4;
  for (int k0 = 0; k0 < Kd; k0 += BK) {
    #pragma unroll
    for (int u = 0; u < 4; ++u) {
      int kk = k0 + la_q + u;
      float av = 0.0f;
      if (kk < Kd) av = A[(size_t)(m0 + la_m)*Kd + kk];
      As[la_q + u][la_m] = av;
    }
    {
      int kk = k0 + lb_k;
      float4 bv = make_float4(0.f,0.f,0.f,0.f);
      if (kk < Kd && (n0 + lb_j + 3) < N)
        bv = *(const float4*)(Bw + (size_t)kk*N + n0 + lb_j);
      *(float4*)&Bs[lb_k][lb_j] = bv;
    }
    __syncthreads();
    #pragma unroll
    for (int kk = 0; kk < BK; ++kk) {
      float4 av = *(const float4*)&As[kk][tr*4];
      float4 bv = *(const float4*)&Bs[kk][tc*4];
      float a[4] = {av.x, av.y, av.z, av.w};
      float bb[4] = {bv.x, bv.y, bv.z, bv.w};
      #pragma unroll
      for (int me = 0; me < 4; ++me)
        #pragma unroll
        for (int je = 0; je < 4; ++je)
          acc[me][je] += a[me]*bb[je];
    }
    __syncthreads();
  }
  #pragma unroll
  for (int me = 0; me < 4; ++me) {
    int m = m0 + tr*4 + me;
    #pragma unroll
    for (int je = 0; je < 4; ++je) {
      int j = n0 + tc*4 + je;
      if (j >= N) continue;
      float v = acc[me][je];
      if (MODE == 0)      Cout[(size_t)m*N + j]  = v;
      else if (MODE == 1) Cout[(size_t)m*N + j]  = sspf(v + bias[j]);
      else                Cout[(size_t)m*N + j] += v + bias[j];
    }
  }
}

// ---------------- fused edge GEMM + aggregation ----------------
// Wf[e,:] = T[e,:]@W2 + b2;  msg[node,:] = sum_k C_e * Wf[e,:] * x1[nbr_e,:]
// One block per (node-within-chunk, n-tile). BM(=64)=K edges of one node.
__global__ __launch_bounds__(256) void edge_agg_k(const float* __restrict__ T,
    const float* __restrict__ W2, const float* __restrict__ b2,
    const float* __restrict__ cval, const int* __restrict__ nbr,
    const float* __restrict__ x1, float* __restrict__ msg, int baseNode) {
  __shared__ float As[BK][BM];
  __shared__ float Bs[BK][BN];
  __shared__ float red[16][BN];
  const int N = HD, Kd = HD;
  int tid = threadIdx.x;
  int mb = blockIdx.x;
  int n0 = blockIdx.y * BN;
  int node = baseNode + mb;
  int m0 = mb * BM;
  int tr = tid >> 4, tc = tid & 15;
  float acc[4][4] = {};
  int la_m = tid >> 2, la_q = (tid & 3) * 4;
  int lb_k = tid >> 4, lb_j = (tid & 15) * 4;
  for (int k0 = 0; k0 < Kd; k0 += BK) {
    #pragma unroll
    for (int u = 0; u < 4; ++u) {
      int kk = k0 + la_q + u;
      float av = 0.0f;
      if (kk < Kd) av = T[(size_t)(m0 + la_m)*Kd + kk];
      As[la_q + u][la_m] = av;
    }
    {
      int kk = k0 + lb_k;
      float4 bv = make_float4(0.f,0.f,0.f,0.f);
      if (kk < Kd && (n0 + lb_j + 3) < N)
        bv = *(const float4*)(W2 + (size_t)kk*N + n0 + lb_j);
      *(float4*)&Bs[lb_k][lb_j] = bv;
    }
    __syncthreads();
    #pragma unroll
    for (int kk = 0; kk < BK; ++kk) {
      float4 av = *(const float4*)&As[kk][tr*4];
      float4 bv = *(const float4*)&Bs[kk][tc*4];
      float a[4] = {av.x, av.y, av.z, av.w};
      float bb[4] = {bv.x, bv.y, bv.z, bv.w};
      #pragma unroll
      for (int me = 0; me < 4; ++me)
        #pragma unroll
        for (int je = 0; je < 4; ++je)
          acc[me][je] += a[me]*bb[je];
    }
    __syncthreads();
  }
  // epilogue: +b2, *C, *x1[nbr], reduce over the node's 64 edges
  int j0 = n0 + tc*4;
  bool jok = (j0 + 3) < N;
  float4 b2v = jok ? *(const float4*)(b2 + j0) : make_float4(0.f,0.f,0.f,0.f);
  float part[4] = {0.f,0.f,0.f,0.f};
  #pragma unroll
  for (int me = 0; me < 4; ++me) {
    int m = tr*4 + me;
    int eg = node*KNB + m;
    float Ce = cval[eg];
    if (Ce != 0.0f && jok) {
      int nb = nbr[eg];
      float4 xv = *(const float4*)(x1 + (size_t)nb*HD + j0);
      part[0] += (acc[me][0] + b2v.x) * Ce * xv.x;
      part[1] += (acc[me][1] + b2v.y) * Ce * xv.y;
      part[2] += (acc[me][2] + b2v.z) * Ce * xv.z;
      part[3] += (acc[me][3] + b2v.w) * Ce * xv.w;
    }
  }
  *(float4*)&red[tr][tc*4] = make_float4(part[0], part[1], part[2], part[3]);
  __syncthreads();
  if (tid < BN) {
    int j = tid;
    float s = 0.0f;
    #pragma unroll
    for (int r = 0; r < 16; ++r) s += red[r][j];
    if (n0 + j < N) msg[(size_t)node*HD + n0 + j] = s;
  }
}

// ---------------- pooling + output ----------------
__global__ __launch_bounds__(256) void pool_mean_k(const float* __restrict__ h,
                                                   float* __restrict__ pooled) {
  int b = blockIdx.x;
  int c = blockIdx.y*256 + threadIdx.x;
  if (c >= HD) return;
  float s = 0.0f;
  for (int n = 0; n < NPG; ++n) s += h[(size_t)(b*NPG + n)*HD + c];
  pooled[(size_t)b*HD + c] = s * (1.0f/128.0f);
}

__global__ __launch_bounds__(256) void pool_out_k(const float* __restrict__ pooled,
    const float* __restrict__ pw, const float* __restrict__ pb,
    float* __restrict__ out) {
  int b = blockIdx.x;
  int j = blockIdx.y*256 + threadIdx.x;
  if (j >= HD) return;
  float s = pb[j];
  for (int c = 0; c < HD; ++c) s += pooled[(size_t)b*HD + c] * pw[(size_t)c*HD + j];
  out[(size_t)b*HD + j] = s;
}

// ---------------- launch ----------------
extern "C" void kernel_launch(void* const* d_in, const int* in_sizes, int n_in,
                              void* d_out, int out_size, void* d_ws, size_t ws_size,
                              hipStream_t stream) {
  const int*   z    = (const int*)d_in[0];
  const float* pos  = (const float*)d_in[1];
  const float* emb  = (const float*)d_in[2];
  const float* w1   = (const float*)d_in[3];
  const float* b1   = (const float*)d_in[4];
  const float* w2   = (const float*)d_in[5];
  const float* b2   = (const float*)d_in[6];
  const float* l1w  = (const float*)d_in[7];
  const float* l2w  = (const float*)d_in[8];
  const float* l2b  = (const float*)d_in[9];
  const float* ilw  = (const float*)d_in[10];
  const float* ilb  = (const float*)d_in[11];
  const float* pw   = (const float*)d_in[12];
  const float* pb   = (const float*)d_in[13];
  float* ws = (float*)d_ws;
  // workspace layout (float offsets)
  int*   nbr   = (int*)ws;                 // 65536 ints
  float* dist  = ws + 65536;               // 65536
  float* cv    = ws + 131072;              // 65536
  float* ea    = ws + 196608;              // 3,276,800
  float* h     = ws + 3473408;             // 614,400
  float* x1    = ws + 4087808;             // 614,400
  float* msg   = ws + 4702208;             // 614,400
  float* mtmp  = ws + 5316608;             // 614,400
  float* pooled= ws + 5931008;             // 4,800
  float* tbuf  = ws + 5935808;             // 4,915,200 (128-node chunk of t)
  float* out   = (float*)d_out;

  build_graph_k<<<16, 64, 0, stream>>>(pos, nbr, dist, cv);
  ea_k<<<(EE*GG + 255)/256, 256, 0, stream>>>(dist, ea);
  embed_k<<<NN, 256, 0, stream>>>(z, emb, h);

  dim3 g16(16, 10), g128(128, 10);
  for (int l = 0; l < LL; ++l) {
    // x1 = h @ lin1_w[l]
    gemm_k<0><<<g16, 256, 0, stream>>>(h, l1w + (size_t)l*360000, nullptr, x1, NN, HD, HD);
    for (int c = 0; c < 8; ++c) {
      // t = ssp(ea @ mlp_w1[l] + mlp_b1[l])   (8192-edge chunk)
      gemm_k<1><<<g128, 256, 0, stream>>>(ea + (size_t)c*8192*GG, w1 + (size_t)l*30000,
                                          b1 + (size_t)l*600, tbuf, 8192, HD, GG);
      // msg = sum_k C * (t@w2 + b2) * x1[nbr]
      edge_agg_k<<<g128, 256, 0, stream>>>(tbuf, w2 + (size_t)l*360000, b2 + (size_t)l*600,
                                           cv, nbr, x1, msg, c*128);
    }
    // mtmp = ssp(msg @ lin2_w[l] + lin2_b[l])
    gemm_k<1><<<g16, 256, 0, stream>>>(msg, l2w + (size_t)l*360000, l2b + (size_t)l*600,
                                       mtmp, NN, HD, HD);
    // h += mtmp @ int_lin_w[l] + int_lin_b[l]
    gemm_k<2><<<g16, 256, 0, stream>>>(mtmp, ilw + (size_t)l*360000, ilb + (size_t)l*600,
                                       h, NN, HD, HD);
  }
  pool_mean_k<<<dim3(NB, 3), 256, 0, stream>>>(h, pooled);
  pool_out_k<<<dim3(NB, 3), 256, 0, stream>>>(pooled, pw, pb, out);
}

// Round 2
// 2814.388 us; speedup vs baseline: 2.7883x; 2.7883x over previous
//
#include <hip/hip_runtime.h>
#include <cmath>

#define NB   8
#define NPG  128
#define NN   1024
#define KNB  64
#define HD   600
#define GG   50
#define LL   6
#define EE   (NN*KNB)   // 65536 edges

typedef __attribute__((ext_vector_type(8))) short short8;
typedef __attribute__((ext_vector_type(4))) float f32x4;

__device__ __forceinline__ short f2b(float f) {
  union { float f; unsigned u; } v; v.f = f;
  unsigned u = v.u;
  u += 0x7fffu + ((u >> 16) & 1u);
  return (short)(u >> 16);
}

__device__ __forceinline__ float sspf(float x) {
  float sp = (x > 20.0f) ? x : log1pf(expf(x));
  return sp - 0.69314718055994531f;
}

// ---------------- graph build: one block per node ----------------
__global__ __launch_bounds__(128) void build_graph_k(const float* __restrict__ pos,
        int* __restrict__ nbr, float* __restrict__ dist, float* __restrict__ cval) {
#pragma clang fp contract(off)
  __shared__ float d2s[128];
  __shared__ int scnt;
  int i = blockIdx.x;
  int li = i & 127;
  int base = i - li;
  int j = threadIdx.x;
  if (j == 0) scnt = 0;
  float px = pos[3*i], py = pos[3*i+1], pz = pos[3*i+2];
  int gj = base + j;
  float dx = px - pos[3*gj], dy = py - pos[3*gj+1], dz = pz - pos[3*gj+2];
  float d2 = dx*dx + dy*dy + dz*dz;
  bool valid = (j != li) && (d2 <= 100.0f);
  d2s[j] = valid ? d2 : 3.0e38f;
  __syncthreads();
  if (valid) {
    atomicAdd(&scnt, 1);
    int rank = 0;
    for (int j2 = 0; j2 < 128; ++j2) {
      float o = d2s[j2];
      rank += (o < d2 || (o == d2 && j2 < j)) ? 1 : 0;
    }
    if (rank < KNB) {
      int e = i*KNB + rank;
      nbr[e] = gj;
      float d = sqrtf(d2);
      dist[e] = d;
      cval[e] = 0.5f * (cosf(d * 0.31415926535897931f) + 1.0f);
    }
  }
  __syncthreads();
  int cnt = scnt; if (cnt > KNB) cnt = KNB;
  if (j < KNB && j >= cnt) {
    int e = i*KNB + j;
    nbr[e] = i; dist[e] = 0.0f; cval[e] = 0.0f;
  }
}

// ---------------- gaussian smearing -> bf16, K padded to 64 ----------------
__global__ __launch_bounds__(256) void ea_k(const float* __restrict__ dist,
                                            short* __restrict__ eab) {
  int idx = blockIdx.x*256 + threadIdx.x;
  if (idx >= EE*64) return;
  int e = idx >> 6, g = idx & 63;
  float v = 0.0f;
  if (g < GG) {
    const float step = 10.0f/49.0f;
    const float coeff = -0.5f/(step*step);
    float dd = dist[e] - step*(float)g;
    v = expf(coeff*dd*dd);
  }
  eab[idx] = f2b(v);
}

// ---------------- weight conversions: fp32 [k][n] -> bf16 [n][k] padded ----------------
__global__ __launch_bounds__(256) void conv_w1_k(const float* __restrict__ w1,
                                                 short* __restrict__ w1b) {
  int idx = blockIdx.x*256 + threadIdx.x;
  if (idx >= LL*640*64) return;
  int l = idx / (640*64); int rem = idx - l*640*64;
  int n = rem >> 6, k = rem & 63;
  float v = (n < HD && k < GG) ? w1[(size_t)l*GG*HD + (size_t)k*HD + n] : 0.0f;
  w1b[idx] = f2b(v);
}

__global__ __launch_bounds__(256) void conv_w2_k(const float* __restrict__ w2,
                                                 short* __restrict__ w2b) {
  int idx = blockIdx.x*256 + threadIdx.x;
  if (idx >= LL*640*608) return;
  int l = idx / (640*608); int rem = idx - l*640*608;
  int n = rem / 608, k = rem - n*608;
  float v = (n < HD && k < HD) ? w2[(size_t)l*HD*HD + (size_t)k*HD + n] : 0.0f;
  w2b[idx] = f2b(v);
}

// ---------------- embedding ----------------
__global__ __launch_bounds__(256) void embed_k(const int* __restrict__ z,
        const float* __restrict__ emb, float* __restrict__ h) {
  int i = blockIdx.x;
  int zi = z[i];
  for (int j = threadIdx.x; j < HD; j += 256)
    h[(size_t)i*HD + j] = emb[(size_t)zi*HD + j];
}

// ---------------- MFMA edge kernels ----------------
// Tile: 64 rows (edges) x 128 cols (features), BK=32, 4 waves.
// A: bf16 [M][lda] row-major.  B: bf16 [n][k] row-major, padded (rows to 640, cols to ldb).
// MODE 0: tout[row][j] = bf16(ssp(acc + bias[j])), stride 608, pads zeroed.
// MODE 1: msg[node][j] = sum_e (acc + bias[j]) * cval[e] * x1[nbr[e]][j]  (64 edges = 1 node/block)
template<int MODE>
__global__ __launch_bounds__(256) void mfma_edge_k(
    const short* __restrict__ A, int lda, int Kd,
    const short* __restrict__ Bw, int ldb,
    const float* __restrict__ bias,
    short* __restrict__ tout,
    const float* __restrict__ cval, const int* __restrict__ nbr,
    const float* __restrict__ x1, float* __restrict__ msg, int nodeBase) {
  __shared__ __align__(16) short As[64*40];
  __shared__ __align__(16) short Bs[128*40];
  __shared__ float cvs[64];
  __shared__ int nbs[64];
  int tid = threadIdx.x;
  int lane = tid & 63, wv = tid >> 6;
  int col = lane & 15, quad = lane >> 4;
  int m0 = blockIdx.x * 64;
  int n0 = blockIdx.y * 128;
  f32x4 acc[4][2] = {};
  if (MODE == 1 && tid < 64) {
    int eg = (nodeBase + blockIdx.x)*KNB + tid;
    cvs[tid] = cval[eg];
    nbs[tid] = nbr[eg];
  }
  int arow = tid >> 2, aseg = tid & 3;
  for (int k0 = 0; k0 < Kd; k0 += 32) {
    *(short8*)&As[arow*40 + aseg*8] =
        *(const short8*)(A + (size_t)(m0 + arow)*lda + k0 + aseg*8);
    #pragma unroll
    for (int rep = 0; rep < 2; ++rep) {
      int s = tid + rep*256;
      int brow = s >> 2, bseg = s & 3;
      *(short8*)&Bs[brow*40 + bseg*8] =
          *(const short8*)(Bw + (size_t)(n0 + brow)*ldb + k0 + bseg*8);
    }
    __syncthreads();
    short8 bf[2];
    #pragma unroll
    for (int jt = 0; jt < 2; ++jt)
      bf[jt] = *(const short8*)&Bs[(wv*32 + jt*16 + col)*40 + quad*8];
    #pragma unroll
    for (int mt = 0; mt < 4; ++mt) {
      short8 af = *(const short8*)&As[(mt*16 + col)*40 + quad*8];
      #pragma unroll
      for (int jt = 0; jt < 2; ++jt)
        acc[mt][jt] = __builtin_amdgcn_mfma_f32_16x16x32_bf16(af, bf[jt], acc[mt][jt], 0, 0, 0);
    }
    __syncthreads();
  }
  if (MODE == 0) {
    #pragma unroll
    for (int jt = 0; jt < 2; ++jt) {
      int j = n0 + wv*32 + jt*16 + col;
      if (j >= 608) continue;
      float bj = (j < HD) ? bias[j] : 0.0f;
      #pragma unroll
      for (int mt = 0; mt < 4; ++mt)
        #pragma unroll
        for (int r = 0; r < 4; ++r) {
          int row = m0 + mt*16 + quad*4 + r;
          float v = (j < HD) ? sspf(acc[mt][jt][r] + bj) : 0.0f;
          tout[(size_t)row*608 + j] = f2b(v);
        }
    }
  } else {
    int node = nodeBase + blockIdx.x;
    #pragma unroll
    for (int jt = 0; jt < 2; ++jt) {
      int j = n0 + wv*32 + jt*16 + col;
      bool jok = j < HD;
      float bj = jok ? bias[j] : 0.0f;
      float s = 0.0f;
      #pragma unroll
      for (int mt = 0; mt < 4; ++mt)
        #pragma unroll
        for (int r = 0; r < 4; ++r) {
          int e = mt*16 + quad*4 + r;
          float Ce = cvs[e];
          if (jok && Ce != 0.0f) {
            float xv = x1[(size_t)nbs[e]*HD + j];
            s += (acc[mt][jt][r] + bj) * Ce * xv;
          }
        }
      s += __shfl_xor(s, 16);
      s += __shfl_xor(s, 32);
      if (quad == 0 && jok) msg[(size_t)node*HD + j] = s;
    }
  }
}

// ---------------- tiled fp32 GEMM (node GEMMs) ----------------
#define BM 64
#define BN 64
#define BK 16

template<int MODE>
__global__ __launch_bounds__(256) void gemm_k(const float* __restrict__ A,
    const float* __restrict__ Bw, const float* __restrict__ bias,
    float* __restrict__ Cout, int M, int N, int Kd) {
  __shared__ float Asf[BK][BM];
  __shared__ float Bsf[BK][BN];
  int tid = threadIdx.x;
  int m0 = blockIdx.x * BM, n0 = blockIdx.y * BN;
  int tr = tid >> 4, tc = tid & 15;
  float acc[4][4] = {};
  int la_m = tid >> 2, la_q = (tid & 3) * 4;
  int lb_k = tid >> 4, lb_j = (tid & 15) * 4;
  for (int k0 = 0; k0 < Kd; k0 += BK) {
    #pragma unroll
    for (int u = 0; u < 4; ++u) {
      int kk = k0 + la_q + u;
      float av = 0.0f;
      if (kk < Kd) av = A[(size_t)(m0 + la_m)*Kd + kk];
      Asf[la_q + u][la_m] = av;
    }
    {
      int kk = k0 + lb_k;
      float4 bv = make_float4(0.f,0.f,0.f,0.f);
      if (kk < Kd && (n0 + lb_j + 3) < N)
        bv = *(const float4*)(Bw + (size_t)kk*N + n0 + lb_j);
      *(float4*)&Bsf[lb_k][lb_j] = bv;
    }
    __syncthreads();
    #pragma unroll
    for (int kk = 0; kk < BK; ++kk) {
      float4 av = *(const float4*)&Asf[kk][tr*4];
      float4 bv = *(const float4*)&Bsf[kk][tc*4];
      float a[4] = {av.x, av.y, av.z, av.w};
      float bb[4] = {bv.x, bv.y, bv.z, bv.w};
      #pragma unroll
      for (int me = 0; me < 4; ++me)
        #pragma unroll
        for (int je = 0; je < 4; ++je)
          acc[me][je] += a[me]*bb[je];
    }
    __syncthreads();
  }
  #pragma unroll
  for (int me = 0; me < 4; ++me) {
    int m = m0 + tr*4 + me;
    #pragma unroll
    for (int je = 0; je < 4; ++je) {
      int j = n0 + tc*4 + je;
      if (j >= N) continue;
      float v = acc[me][je];
      if (MODE == 0)      Cout[(size_t)m*N + j]  = v;
      else if (MODE == 1) Cout[(size_t)m*N + j]  = sspf(v + bias[j]);
      else                Cout[(size_t)m*N + j] += v + bias[j];
    }
  }
}

// ---------------- pooling + output ----------------
__global__ __launch_bounds__(256) void pool_mean_k(const float* __restrict__ h,
                                                   float* __restrict__ pooled) {
  int b = blockIdx.x;
  int c = blockIdx.y*256 + threadIdx.x;
  if (c >= HD) return;
  float s = 0.0f;
  for (int n = 0; n < NPG; ++n) s += h[(size_t)(b*NPG + n)*HD + c];
  pooled[(size_t)b*HD + c] = s * (1.0f/128.0f);
}

__global__ __launch_bounds__(256) void pool_out_k(const float* __restrict__ pooled,
    const float* __restrict__ pw, const float* __restrict__ pb,
    float* __restrict__ out) {
  int b = blockIdx.x;
  int j = blockIdx.y*256 + threadIdx.x;
  if (j >= HD) return;
  float s = pb[j];
  for (int c = 0; c < HD; ++c) s += pooled[(size_t)b*HD + c] * pw[(size_t)c*HD + j];
  out[(size_t)b*HD + j] = s;
}

// ---------------- launch ----------------
extern "C" void kernel_launch(void* const* d_in, const int* in_sizes, int n_in,
                              void* d_out, int out_size, void* d_ws, size_t ws_size,
                              hipStream_t stream) {
  const int*   z    = (const int*)d_in[0];
  const float* pos  = (const float*)d_in[1];
  const float* emb  = (const float*)d_in[2];
  const float* w1   = (const float*)d_in[3];
  const float* b1   = (const float*)d_in[4];
  const float* w2   = (const float*)d_in[5];
  const float* b2   = (const float*)d_in[6];
  const float* l1w  = (const float*)d_in[7];
  const float* l2w  = (const float*)d_in[8];
  const float* l2b  = (const float*)d_in[9];
  const float* ilw  = (const float*)d_in[10];
  const float* ilb  = (const float*)d_in[11];
  const float* pw   = (const float*)d_in[12];
  const float* pb   = (const float*)d_in[13];
  float* ws = (float*)d_ws;
  // workspace layout (float offsets)
  int*   nbr   = (int*)ws;                  // 65536
  float* cv    = ws + 65536;                // 65536
  float* dist  = ws + 131072;               // 65536
  float* pooled= ws + 196608;               // 4800 (+pad to 201728)
  float* h     = ws + 201728;               // 614400
  float* x1    = ws + 816128;               // 614400 (also reused as mtmp)
  float* msg   = ws + 1430528;              // 614400
  short* eab   = (short*)(ws + 2044928);    // 65536*64 shorts = 2097152 f
  short* w1b   = (short*)(ws + 4142080);    // 6*640*64  shorts = 122880 f
  short* w2b   = (short*)(ws + 4264960);    // 6*640*608 shorts = 1167360 f
  short* tbuf  = (short*)(ws + 5432320);    // 16384*608 shorts = 4980736 f
                                            // end = 10413056 floats = 41.7 MB
  float* mtmp  = x1;
  float* out   = (float*)d_out;

  build_graph_k<<<NN, 128, 0, stream>>>(pos, nbr, dist, cv);
  ea_k<<<(EE*64 + 255)/256, 256, 0, stream>>>(dist, eab);
  conv_w1_k<<<(LL*640*64 + 255)/256, 256, 0, stream>>>(w1, w1b);
  conv_w2_k<<<(LL*640*608 + 255)/256, 256, 0, stream>>>(w2, w2b);
  embed_k<<<NN, 256, 0, stream>>>(z, emb, h);

  dim3 g16(16, 10);
  dim3 ge(256, 5);
  for (int l = 0; l < LL; ++l) {
    // x1 = h @ lin1_w[l]   (fp32)
    gemm_k<0><<<g16, 256, 0, stream>>>(h, l1w + (size_t)l*360000, nullptr, x1, NN, HD, HD);
    for (int c = 0; c < 4; ++c) {
      // t = ssp(ea @ mlp_w1[l] + b1)  -> bf16 tbuf  (16384-edge chunk)
      mfma_edge_k<0><<<ge, 256, 0, stream>>>(
          eab + (size_t)c*16384*64, 64, 64,
          w1b + (size_t)l*640*64, 64,
          b1 + (size_t)l*HD, tbuf,
          nullptr, nullptr, nullptr, nullptr, 0);
      // msg = sum_k C * (t@w2 + b2) * x1[nbr]
      mfma_edge_k<1><<<ge, 256, 0, stream>>>(
          tbuf, 608, 608,
          w2b + (size_t)l*640*608, 608,
          b2 + (size_t)l*HD, nullptr,
          cv, nbr, x1, msg, c*256);
    }
    // mtmp = ssp(msg @ lin2_w[l] + lin2_b[l])   (fp32; mtmp aliases x1, safe: x1 consumed)
    gemm_k<1><<<g16, 256, 0, stream>>>(msg, l2w + (size_t)l*360000, l2b + (size_t)l*HD,
                                       mtmp, NN, HD, HD);
    // h += mtmp @ int_lin_w[l] + int_lin_b[l]
    gemm_k<2><<<g16, 256, 0, stream>>>(mtmp, ilw + (size_t)l*360000, ilb + (size_t)l*HD,
                                       h, NN, HD, HD);
  }
  pool_mean_k<<<dim3(NB, 3), 256, 0, stream>>>(h, pooled);
  pool_out_k<<<dim3(NB, 3), 256, 0, stream>>>(pooled, pw, pb, out);
}